// Round 3
// baseline (113.192 us; speedup 1.0000x reference)
//
#include <hip/hip_runtime.h>
#include <math.h>

#define NEL   4096
#define NT    512            // fused kernel: 8 waves
#define HALF  256            // threads per array half
#define EPT   (NEL / HALF)   // 16 sorted/scatter elements per thread
#define CPT   (NEL / NT)     // 8 correlation elements per thread
#define JSEG  4              // j-segments for partial counting
#define JLEN  (NEL / JSEG)   // 1024
#define CB    256            // count_kernel block size

// ---------------------------------------------------------------------------
// Kernel A: partial stable descending-rank counts. grid (16, JSEG, 2).
// part[(arr*JSEG + seg)*NEL + i] = #{ j in seg : x_j > x_i or (== and j<i) }.
// Plain stores to disjoint slots -> no memset, no atomics, 128 blocks.
// ---------------------------------------------------------------------------
__global__ __launch_bounds__(CB)
void count_kernel(const float* __restrict__ pred,
                  const float* __restrict__ target,
                  int* __restrict__ part) {
  __shared__ float jv[JLEN];
  const int arr = blockIdx.z;
  const float* __restrict__ x = arr ? target : pred;
  const int i     = blockIdx.x * CB + threadIdx.x;
  const int jbase = blockIdx.y * JLEN;

  for (int t = threadIdx.x; t < JLEN; t += CB) jv[t] = x[jbase + t];
  const float xi = x[i];
  __syncthreads();

  const float4* jv4 = (const float4*)jv;
  int c = 0;
#pragma unroll 4
  for (int t4 = 0; t4 < JLEN / 4; t4++) {
    const float4 v = jv4[t4];        // wave-uniform LDS broadcast
    const int j = jbase + t4 * 4;
    c += (v.x > xi || (v.x == xi && j + 0 < i)) ? 1 : 0;
    c += (v.y > xi || (v.y == xi && j + 1 < i)) ? 1 : 0;
    c += (v.z > xi || (v.z == xi && j + 2 < i)) ? 1 : 0;
    c += (v.w > xi || (v.w == xi && j + 3 < i)) ? 1 : 0;
  }
  part[(arr * JSEG + blockIdx.y) * NEL + i] = c;
}

// ---------------------------------------------------------------------------
// Kernel B (one block, 512 threads, halves aligned on barriers):
//   sum partials -> scatter sorted -> double prefix sums -> D&C PAV
//   (m<=8 barrier-free in own range, m=16..2048 barriered) -> ranks in-place
//   -> Pearson correlation -> loss.
// LDS ~= 130 KB (fits 160 KB/CU).
// ---------------------------------------------------------------------------
__global__ __launch_bounds__(NT)
void pav_loss_kernel(const float* __restrict__ pred,
                     const float* __restrict__ target,
                     const int* __restrict__ part,
                     float* __restrict__ loss_out) {
  __shared__ float  s_val[2][NEL];     // sorted values; later rank_sorted
  __shared__ double s_P[2][NEL + 1];   // prefix sums of z
  __shared__ int    s_cnt[2][NEL];     // counts -> block stamps -> bstart
  __shared__ double s_wsum[2][HALF / 64];
  __shared__ int    s_nb[2];
  __shared__ double s_red[NT / 64][5];

  const int tid  = threadIdx.x;
  const int arr  = tid >> 8;           // 0: pred, 1: target
  const int tA   = tid & (HALF - 1);
  const int lane = tid & 63;
  const int wA   = tA >> 6;            // wave within half, 0..3
  const float* __restrict__ x = arr ? target : pred;
  const int base = tA * EPT;

  // ---- phase 0: sum JSEG partials for own 16 original indices -------------
  int   r[EPT];
  float xv[EPT];
#pragma unroll
  for (int e = 0; e < EPT; e++) {
    const int i = base + e;
    int c = 0;
#pragma unroll
    for (int s = 0; s < JSEG; s++) c += part[(arr * JSEG + s) * NEL + i];
    r[e] = c;                          // sorted position of original element i
    s_cnt[arr][i] = c;                 // publish for corr-index capture
    xv[e] = x[i];
  }
  __syncthreads();

  // ---- phase 1: capture corr sorted-positions; scatter into sorted order --
  int rp[CPT], rt[CPT];
#pragma unroll
  for (int e = 0; e < CPT; e++) {
    const int i = tid * CPT + e;
    rp[e] = s_cnt[0][i];
    rt[e] = s_cnt[1][i];
  }
#pragma unroll
  for (int e = 0; e < EPT; e++) s_val[arr][r[e]] = xv[e];
  __syncthreads();

  // ---- phase 2: double prefix sums of z_p = s_p - (NEL - p) ---------------
  double c[EPT];
  double acc = 0.0;
#pragma unroll
  for (int e = 0; e < EPT; e++) {
    const int p = base + e;
    acc += (double)s_val[arr][p] - (double)(NEL - p);
    c[e] = acc;
  }
  double sc = acc;                     // wave-inclusive scan of thread totals
#pragma unroll
  for (int d = 1; d < 64; d <<= 1) {
    const double o = __shfl_up(sc, d, 64);
    if (lane >= d) sc += o;
  }
  if (lane == 63) s_wsum[arr][wA] = sc;
  __syncthreads();
  if (tA == 0) {                       // serial exclusive scan over 4 waves
    double a2 = 0.0;
    for (int w = 0; w < HALF / 64; w++) {
      const double t = s_wsum[arr][w];
      s_wsum[arr][w] = a2;
      a2 += t;
    }
  }
  __syncthreads();
  const double excl = s_wsum[arr][wA] + (sc - acc);
#pragma unroll
  for (int e = 0; e < EPT; e++) s_P[arr][base + e + 1] = excl + c[e];
  if (tA == 0) s_P[arr][0] = 0.0;
#pragma unroll
  for (int e = 0; e < EPT; e++) s_cnt[arr][base + e] = 1;
  __syncthreads();

  // ---- D&C PAV (non-increasing isotonic) ----------------------------------
  // invariant: block [a,b] has s_cnt[a] == s_cnt[b] == b-a+1
  // Levels 2m <= EPT touch only this thread's own range: NO barriers needed.
  for (int m = 1; m <= EPT / 2; m <<= 1) {
    const int rpt = EPT / (2 * m);     // regions per thread at this level
    for (int t = tA * rpt; t < (tA + 1) * rpt; t++) {
      const int lo = t * 2 * m, mid = lo + m, hi = lo + 2 * m;
      const int llen = s_cnt[arr][mid - 1];
      int cs = mid - llen;
      const int rlen = s_cnt[arr][mid];
      int ce = mid + rlen - 1;
      const double mL = (s_P[arr][mid] - s_P[arr][cs]) / (double)llen;
      const double mR = (s_P[arr][ce + 1] - s_P[arr][mid]) / (double)rlen;
      if (mL <= mR) {
        double mu = (s_P[arr][ce + 1] - s_P[arr][cs]) / (double)(ce - cs + 1);
        bool changed = true;
        while (changed) {
          changed = false;
          while (cs > lo) {
            const int l2 = s_cnt[arr][cs - 1];
            const double m2 = (s_P[arr][cs] - s_P[arr][cs - l2]) / (double)l2;
            if (m2 <= mu) {
              cs -= l2;
              mu = (s_P[arr][ce + 1] - s_P[arr][cs]) / (double)(ce - cs + 1);
              changed = true;
            } else break;
          }
          while (ce < hi - 1) {
            const int l2 = s_cnt[arr][ce + 1];
            const double m2 = (s_P[arr][ce + 1 + l2] - s_P[arr][ce + 1]) / (double)l2;
            if (m2 >= mu) {
              ce += l2;
              mu = (s_P[arr][ce + 1] - s_P[arr][cs]) / (double)(ce - cs + 1);
              changed = true;
            } else break;
          }
        }
        const int len = ce - cs + 1;
        s_cnt[arr][cs] = len;
        s_cnt[arr][ce] = len;
      }
    }
  }
  __syncthreads();
  // Levels 2m > EPT: cross-thread, barrier per level (m = 16 .. 2048).
  for (int m = EPT; m < NEL; m <<= 1) {
    const int nmerge = NEL / (2 * m);
    for (int t = tA; t < nmerge; t += HALF) {
      const int lo = t * 2 * m, mid = lo + m, hi = lo + 2 * m;
      const int llen = s_cnt[arr][mid - 1];
      int cs = mid - llen;
      const int rlen = s_cnt[arr][mid];
      int ce = mid + rlen - 1;
      const double mL = (s_P[arr][mid] - s_P[arr][cs]) / (double)llen;
      const double mR = (s_P[arr][ce + 1] - s_P[arr][mid]) / (double)rlen;
      if (mL <= mR) {
        double mu = (s_P[arr][ce + 1] - s_P[arr][cs]) / (double)(ce - cs + 1);
        bool changed = true;
        while (changed) {
          changed = false;
          while (cs > lo) {
            const int l2 = s_cnt[arr][cs - 1];
            const double m2 = (s_P[arr][cs] - s_P[arr][cs - l2]) / (double)l2;
            if (m2 <= mu) {
              cs -= l2;
              mu = (s_P[arr][ce + 1] - s_P[arr][cs]) / (double)(ce - cs + 1);
              changed = true;
            } else break;
          }
          while (ce < hi - 1) {
            const int l2 = s_cnt[arr][ce + 1];
            const double m2 = (s_P[arr][ce + 1 + l2] - s_P[arr][ce + 1]) / (double)l2;
            if (m2 >= mu) {
              ce += l2;
              mu = (s_P[arr][ce + 1] - s_P[arr][cs]) / (double)(ce - cs + 1);
              changed = true;
            } else break;
          }
        }
        const int len = ce - cs + 1;
        s_cnt[arr][cs] = len;
        s_cnt[arr][ce] = len;
      }
    }
    __syncthreads();
  }

  // ---- walk block list (s_cnt aliased to bstart; reads lead writes) -------
  if (tA == 0) {
    int s = 0, b = 0;
    while (s < NEL) {
      const int cc = s_cnt[arr][s];    // read BEFORE aliased write
      s_cnt[arr][b] = s;
      b++;
      s += cc;
    }
    s_nb[arr] = b;
  }
  __syncthreads();
  const int nb = s_nb[arr];

  // ---- rank at each sorted position; publish in-place into s_val ----------
#pragma unroll
  for (int e = 0; e < EPT; e++) {
    const int p = base + e;
    int loB = 0, hiB = nb - 1;
    while (loB < hiB) {
      const int md = (loB + hiB + 1) >> 1;
      if (s_cnt[arr][md] <= p) loB = md; else hiB = md - 1;
    }
    const int st = s_cnt[arr][loB];
    const int en = (loB + 1 < nb) ? s_cnt[arr][loB + 1] : NEL;
    const double v = (s_P[arr][en] - s_P[arr][st]) / (double)(en - st);
    s_val[arr][p] = (float)((double)s_val[arr][p] - v);  // own-addr RAW: safe
  }
  __syncthreads();

  // ---- Pearson correlation: gather both rank vectors by sorted position ---
  double Sp = 0.0, St = 0.0, Spp = 0.0, Stt = 0.0, Spt = 0.0;
#pragma unroll
  for (int e = 0; e < CPT; e++) {
    const double p = (double)s_val[0][rp[e]];   // pred rank at orig index
    const double t = (double)s_val[1][rt[e]];   // target rank at same index
    Sp += p; St += t; Spp += p * p; Stt += t * t; Spt += p * t;
  }
#pragma unroll
  for (int d = 32; d > 0; d >>= 1) {
    Sp  += __shfl_down(Sp,  d, 64);
    St  += __shfl_down(St,  d, 64);
    Spp += __shfl_down(Spp, d, 64);
    Stt += __shfl_down(Stt, d, 64);
    Spt += __shfl_down(Spt, d, 64);
  }
  const int wid = tid >> 6;
  if (lane == 0) {
    s_red[wid][0] = Sp;  s_red[wid][1] = St;  s_red[wid][2] = Spp;
    s_red[wid][3] = Stt; s_red[wid][4] = Spt;
  }
  __syncthreads();
  if (tid == 0) {
    double a0 = 0, a1 = 0, a2 = 0, a3 = 0, a4 = 0;
    for (int w = 0; w < NT / 64; w++) {
      a0 += s_red[w][0]; a1 += s_red[w][1]; a2 += s_red[w][2];
      a3 += s_red[w][3]; a4 += s_red[w][4];
    }
    const double n  = (double)NEL;
    const double mp = a0 / n, mt = a1 / n;
    const double cov = a4 - n * mp * mt;
    const double vp  = a2 - n * mp * mp;
    const double vt  = a3 - n * mt * mt;
    loss_out[0] = (float)(1.0 - cov / sqrt(vp * vt));
  }
}

// ---------------------------------------------------------------------------
extern "C" void kernel_launch(void* const* d_in, const int* in_sizes, int n_in,
                              void* d_out, int out_size, void* d_ws, size_t ws_size,
                              hipStream_t stream) {
  const float* pred   = (const float*)d_in[0];
  const float* target = (const float*)d_in[1];
  int*   part = (int*)d_ws;                // 2 * JSEG * NEL ints = 128 KB
  float* out  = (float*)d_out;

  hipLaunchKernelGGL(count_kernel, dim3(NEL / CB, JSEG, 2), dim3(CB), 0,
                     stream, pred, target, part);
  hipLaunchKernelGGL(pav_loss_kernel, dim3(1), dim3(NT), 0, stream,
                     pred, target, part, out);
}

// Round 4
// 92.448 us; speedup vs baseline: 1.2244x; 1.2244x over previous
//
#include <hip/hip_runtime.h>
#include <math.h>

#define NEL   4096
#define NT    1024
#define HALF  512            // threads per array half (sorted-range ownership)
#define EPT   8              // sorted elements per half-thread
#define CPT   4              // original/corr indices per thread (both arrays)
#define JSEG  8              // j-segments for partial counting
#define JLEN  (NEL / JSEG)   // 512
#define CB    256            // count_kernel block size

// wave-synchronous LDS fence: lanes are lockstep; lgkmcnt(0) drains this
// wave's ds ops; memory clobber stops compiler reordering/caching.
#define WSYNC() asm volatile("s_waitcnt lgkmcnt(0)" ::: "memory")

// ---------------------------------------------------------------------------
// Kernel A: partial stable descending-rank counts. grid (16, JSEG, 2).
// part[(arr*JSEG+seg)*NEL + i] = #{ j in seg : x_j > x_i or (== and j<i) }.
// Disjoint plain stores -> no memset, no atomics. 256 blocks -> 1/CU.
// ---------------------------------------------------------------------------
__global__ __launch_bounds__(CB)
void count_kernel(const float* __restrict__ pred,
                  const float* __restrict__ target,
                  int* __restrict__ part) {
  __shared__ float jv[JLEN];
  const int arr = blockIdx.z;
  const float* __restrict__ x = arr ? target : pred;
  const int i     = blockIdx.x * CB + threadIdx.x;
  const int jbase = blockIdx.y * JLEN;

  for (int t = threadIdx.x; t < JLEN; t += CB) jv[t] = x[jbase + t];
  const float xi = x[i];
  __syncthreads();

  const float4* jv4 = (const float4*)jv;
  int c = 0;
#pragma unroll 4
  for (int t4 = 0; t4 < JLEN / 4; t4++) {
    const float4 v = jv4[t4];
    const int j = jbase + 4 * t4;
    c += (v.x > xi || (v.x == xi && j + 0 < i)) ? 1 : 0;
    c += (v.y > xi || (v.y == xi && j + 1 < i)) ? 1 : 0;
    c += (v.z > xi || (v.z == xi && j + 2 < i)) ? 1 : 0;
    c += (v.w > xi || (v.w == xi && j + 3 < i)) ? 1 : 0;
  }
  part[(arr * JSEG + blockIdx.y) * NEL + i] = c;
}

// ---------------------------------------------------------------------------
// single-boundary pool merge of two adjacent isotonic regions [lo,mid),[mid,hi)
// invariant: block [a,b] has C[a] == C[b] == b-a+1
// ---------------------------------------------------------------------------
__device__ inline void pav_merge(double* P, int* C, const int lo, const int mid,
                                 const int hi) {
  const int llen = C[mid - 1];
  int cs = mid - llen;
  const int rlen = C[mid];
  int ce = mid + rlen - 1;
  const double mL = (P[mid] - P[cs]) / (double)llen;
  const double mR = (P[ce + 1] - P[mid]) / (double)rlen;
  if (mL <= mR) {                        // boundary violation -> pool
    double mu = (P[ce + 1] - P[cs]) / (double)(ce - cs + 1);
    bool changed = true;
    while (changed) {
      changed = false;
      while (cs > lo) {                  // absorb left blocks with mean <= mu
        const int l2 = C[cs - 1];
        const double m2 = (P[cs] - P[cs - l2]) / (double)l2;
        if (m2 <= mu) {
          cs -= l2;
          mu = (P[ce + 1] - P[cs]) / (double)(ce - cs + 1);
          changed = true;
        } else break;
      }
      while (ce < hi - 1) {              // absorb right blocks with mean >= mu
        const int l2 = C[ce + 1];
        const double m2 = (P[ce + 1 + l2] - P[ce + 1]) / (double)l2;
        if (m2 >= mu) {
          ce += l2;
          mu = (P[ce + 1] - P[cs]) / (double)(ce - cs + 1);
          changed = true;
        } else break;
      }
    }
    const int len = ce - cs + 1;
    C[cs] = len;
    C[ce] = len;
  }
}

// ---------------------------------------------------------------------------
// Kernel B (one block, 1024 threads): 6 block barriers total.
//   coalesced count-sum + scatter -> register prefix -> serial own-range PAV
//   -> wave-sync mid levels -> 3 cross-wave levels (first wave per half)
//   -> ranks in place -> Pearson loss. LDS ~= 129 KB.
// ---------------------------------------------------------------------------
__global__ __launch_bounds__(NT)
void pav_loss_kernel(const float* __restrict__ pred,
                     const float* __restrict__ target,
                     const int* __restrict__ part,
                     float* __restrict__ loss_out) {
  __shared__ float  s_val[2][NEL];      // sorted values; later sorted ranks
  __shared__ double s_P[2][NEL + 1];    // prefix sums of z
  __shared__ int    s_cnt[2][NEL];      // block stamps -> bstart list
  __shared__ double s_wsum[2][HALF / 64];
  __shared__ int    s_nb[2];
  __shared__ double s_red[NT / 64][5];

  const int tid  = threadIdx.x;
  const int lane = tid & 63;
  const int wid  = tid >> 6;

  // ---- phase 0: coalesced sum of JSEG partials for orig idx [4tid,4tid+4)
  //      (both arrays), load values, scatter into sorted order -------------
  int rp[CPT], rt[CPT];
  {
    const int4* p4 = (const int4*)part;
    int4 a = make_int4(0, 0, 0, 0), b = make_int4(0, 0, 0, 0);
#pragma unroll
    for (int s = 0; s < JSEG; s++) {
      const int4 u = p4[s * (NEL / 4) + tid];
      a.x += u.x; a.y += u.y; a.z += u.z; a.w += u.w;
      const int4 v = p4[(JSEG + s) * (NEL / 4) + tid];
      b.x += v.x; b.y += v.y; b.z += v.z; b.w += v.w;
    }
    rp[0] = a.x; rp[1] = a.y; rp[2] = a.z; rp[3] = a.w;
    rt[0] = b.x; rt[1] = b.y; rt[2] = b.z; rt[3] = b.w;
    const float4 xp = ((const float4*)pred)[tid];
    const float4 xt = ((const float4*)target)[tid];
    s_val[0][rp[0]] = xp.x; s_val[0][rp[1]] = xp.y;
    s_val[0][rp[2]] = xp.z; s_val[0][rp[3]] = xp.w;
    s_val[1][rt[0]] = xt.x; s_val[1][rt[1]] = xt.y;
    s_val[1][rt[2]] = xt.z; s_val[1][rt[3]] = xt.w;
  }
  __syncthreads();                                   // B1

  // ---- sorted-range ownership --------------------------------------------
  const int arr = tid >> 9;            // 0: pred, 1: target
  const int tA  = tid & (HALF - 1);
  const int wA  = tA >> 6;             // wave within half, 0..7
  const int b0  = tA * EPT;
  double* P = s_P[arr];
  int*    C = s_cnt[arr];

  // ---- register prefix of z_p = s_p - (NEL - p) over own 8 elements ------
  double c[EPT];
  {
    double acc = 0.0;
#pragma unroll
    for (int e = 0; e < EPT; e++) {
      const int p = b0 + e;
      acc += (double)s_val[arr][p] - (double)(NEL - p);
      c[e] = acc;
    }
  }
  const double tot = c[EPT - 1];
  double sc = tot;                     // wave-inclusive scan of thread totals
#pragma unroll
  for (int d = 1; d < 64; d <<= 1) {
    const double o = __shfl_up(sc, d, 64);
    if (lane >= d) sc += o;
  }
  if (lane == 63) s_wsum[arr][wA] = sc;
  __syncthreads();                                   // B2
  double wexcl = 0.0;
#pragma unroll
  for (int w = 0; w < HALF / 64; w++)
    wexcl += (w < wA) ? s_wsum[arr][w] : 0.0;
  const double excl = wexcl + (sc - tot);            // == P[b0]
#pragma unroll
  for (int e = 0; e < EPT; e++) P[b0 + 1 + e] = excl + c[e];
  if (lane == 0) P[b0] = excl;         // wave-span base (incl. P[0] = 0)

  // ---- serial left-to-right PAV on own range [b0, b0+8): no sync needed --
  // all P reads are own-written except index b0 (use register excl)
  C[b0] = 1;
  for (int p = b0 + 1; p < b0 + EPT; p++) {
    int cs = p;
    const double Pe = P[p + 1];
    while (cs > b0) {
      const int l2 = C[cs - 1];
      const int lb = cs - l2;
      const double Pcs = P[cs];        // cs > b0: own-written
      const double Plb = (lb == b0) ? excl : P[lb];
      const double mPrev = (Pcs - Plb) / (double)l2;
      const double mCur  = (Pe - Pcs) / (double)(p - cs + 1);
      if (mPrev <= mCur) cs = lb; else break;
    }
    C[cs] = p - cs + 1;
    C[p]  = p - cs + 1;
  }
  WSYNC();   // own wave's P + stamps visible wave-wide (lockstep)

  // ---- within-wave levels m = 8..256 (spans 16..512), wave-synchronous ---
  const int wbase = wA * 512;
#pragma unroll
  for (int m = EPT; m <= 256; m <<= 1) {
    const int nm = 512 / (2 * m);
    if (lane < nm) {
      const int lo = wbase + lane * 2 * m;
      pav_merge(P, C, lo, lo + m, lo + 2 * m);
    }
    WSYNC();
  }
  __syncthreads();                                   // B3

  // ---- cross-wave levels m = 512,1024,2048 + walk: first wave per half ---
  if (wA == 0) {
#pragma unroll
    for (int m = 512; m <= 2048; m <<= 1) {
      const int nm = NEL / (2 * m);
      if (lane < nm) {
        const int lo = lane * 2 * m;
        pav_merge(P, C, lo, lo + m, lo + 2 * m);
      }
      WSYNC();
    }
    if (lane == 0) {                   // walk block list -> bstart (aliased;
      int s = 0, b = 0;                //  reads lead writes)
      while (s < NEL) {
        const int cc = C[s];
        C[b] = s;
        b++;
        s += cc;
      }
      s_nb[arr] = b;
    }
  }
  __syncthreads();                                   // B4

  // ---- rank at own sorted positions, in place -----------------------------
  const int nb = s_nb[arr];
#pragma unroll
  for (int e = 0; e < EPT; e++) {
    const int p = b0 + e;
    int lo = 0, hi = nb - 1;
    while (lo < hi) {
      const int md = (lo + hi + 1) >> 1;
      if (C[md] <= p) lo = md; else hi = md - 1;
    }
    const int st = C[lo];
    const int en = (lo + 1 < nb) ? C[lo + 1] : NEL;
    const double v = (P[en] - P[st]) / (double)(en - st);
    s_val[arr][p] = (float)((double)s_val[arr][p] - v);
  }
  __syncthreads();                                   // B5

  // ---- Pearson loss: gather both rank vectors via captured positions -----
  double Sp = 0.0, Sq = 0.0, Spp = 0.0, Sqq = 0.0, Spq = 0.0;
#pragma unroll
  for (int e = 0; e < CPT; e++) {
    const double p = (double)s_val[0][rp[e]];  // pred rank at orig idx 4tid+e
    const double q = (double)s_val[1][rt[e]];  // target rank at same idx
    Sp += p; Sq += q; Spp += p * p; Sqq += q * q; Spq += p * q;
  }
#pragma unroll
  for (int d = 32; d > 0; d >>= 1) {
    Sp  += __shfl_down(Sp,  d, 64);
    Sq  += __shfl_down(Sq,  d, 64);
    Spp += __shfl_down(Spp, d, 64);
    Sqq += __shfl_down(Sqq, d, 64);
    Spq += __shfl_down(Spq, d, 64);
  }
  if (lane == 0) {
    s_red[wid][0] = Sp;  s_red[wid][1] = Sq;  s_red[wid][2] = Spp;
    s_red[wid][3] = Sqq; s_red[wid][4] = Spq;
  }
  __syncthreads();                                   // B6
  if (tid == 0) {
    double a0 = 0, a1 = 0, a2 = 0, a3 = 0, a4 = 0;
    for (int w = 0; w < NT / 64; w++) {
      a0 += s_red[w][0]; a1 += s_red[w][1]; a2 += s_red[w][2];
      a3 += s_red[w][3]; a4 += s_red[w][4];
    }
    const double n  = (double)NEL;
    const double mp = a0 / n, mq = a1 / n;
    const double cov = a4 - n * mp * mq;
    const double vp  = a2 - n * mp * mp;
    const double vq  = a3 - n * mq * mq;
    loss_out[0] = (float)(1.0 - cov / sqrt(vp * vq));
  }
}

// ---------------------------------------------------------------------------
extern "C" void kernel_launch(void* const* d_in, const int* in_sizes, int n_in,
                              void* d_out, int out_size, void* d_ws, size_t ws_size,
                              hipStream_t stream) {
  const float* pred   = (const float*)d_in[0];
  const float* target = (const float*)d_in[1];
  int*   part = (int*)d_ws;                // 2 * JSEG * NEL ints = 256 KB
  float* out  = (float*)d_out;

  hipLaunchKernelGGL(count_kernel, dim3(NEL / CB, JSEG, 2), dim3(CB), 0,
                     stream, pred, target, part);
  hipLaunchKernelGGL(pav_loss_kernel, dim3(1), dim3(NT), 0, stream,
                     pred, target, part, out);
}